// Round 7
// baseline (615.940 us; speedup 1.0000x reference)
//
#include <hip/hip_runtime.h>

#define BLK 256
#define CAPB 4608         // per-(step,dst-bucket) stream cap: mean 4096, sd 64 (+8 sigma)
#define MAXNBD 512
#define MAXK2 2048
#define OVFN 65536
#define WBITS 13          // idx-window = 8192 edges (32KB per ei half)
#define W1CAP 8928        // window stream cap: mean 8192, sd ~90 (+8 sigma)
#define MAXNW 1024
#define IPTA 32           // k_win: 512 thr * 32 = 16384 entries/block

// ---------------- init: copy compact x (n,10) into strided h (n,16) --------
__global__ void k_init_h(const float* __restrict__ x, float* __restrict__ h, int n) {
    int total = n * 16;
    int gs = gridDim.x * blockDim.x;
    for (int i = blockIdx.x * blockDim.x + threadIdx.x; i < total; i += gs) {
        int row = i >> 4, col = i & 15;
        h[i] = (col < 10) ? x[row * 10 + col] : 0.0f;
    }
}

// ---------------- pass A: bin order entries by idx-window (no gathers) -----
// recs1[w][pos] = (st<<23)|idx
__global__ __launch_bounds__(512) void k_win(const int* __restrict__ orders,
                                             int total, int epo, int NW,
                                             int* __restrict__ gcnt1,
                                             unsigned* __restrict__ recs1,
                                             int* __restrict__ ovf1_cnt,
                                             unsigned* __restrict__ ovf1) {
    __shared__ int bcnt[MAXNW];
    __shared__ int gbase[MAXNW];
    int t = threadIdx.x;
    for (int i = t; i < NW; i += 512) bcnt[i] = 0;
    __syncthreads();

    size_t base = (size_t)blockIdx.x * (512 * IPTA);
    int st0 = (int)(base / (size_t)epo);
    size_t b1 = (size_t)(st0 + 1) * (size_t)epo;   // block spans <= one step boundary

    unsigned recr[IPTA]; int rr[IPTA];
    #pragma unroll
    for (int q = 0; q < IPTA; ++q) {
        size_t g = base + (size_t)q * 512 + t;
        recr[q] = 0xFFFFFFFFu; rr[q] = 0;
        if (g < (size_t)total) {
            int idx = orders[g];
            int st = (g >= b1) ? (st0 + 1) : st0;
            recr[q] = ((unsigned)st << 23) | (unsigned)idx;
            rr[q] = atomicAdd(&bcnt[idx >> WBITS], 1);
        }
    }
    __syncthreads();
    for (int k = t; k < NW; k += 512) {
        int c = bcnt[k];
        gbase[k] = c ? atomicAdd(&gcnt1[k], c) : 0;
    }
    __syncthreads();
    #pragma unroll
    for (int q = 0; q < IPTA; ++q) {
        if (recr[q] != 0xFFFFFFFFu) {
            int idx = (int)(recr[q] & 0x7FFFFFu);
            int key = idx >> WBITS;
            int pos = gbase[key] + rr[q];
            if (pos < W1CAP)
                __builtin_nontemporal_store(recr[q], &recs1[(size_t)key * W1CAP + pos]);
            else {
                int o = atomicAdd(ovf1_cnt, 1);
                if (o < OVFN) ovf1[o] = recr[q];
            }
        }
    }
}

// ---------------- pass B: resolve (d,s) in L2 windows, bin by (st, d>>8) ---
// 2 windows per block, 2 passes (count, scatter); ei streamed exactly once.
__global__ __launch_bounds__(512) void k_bin2(const int* __restrict__ ei, int ne,
                                              const int* __restrict__ gcnt1,
                                              const unsigned* __restrict__ recs1,
                                              int NW, int NBD,
                                              int* __restrict__ gcnt2,
                                              unsigned* __restrict__ recs2,
                                              int* __restrict__ ovf2_cnt,
                                              int2* __restrict__ ovf2) {
    __shared__ int cnt2[MAXK2];
    __shared__ int cur[MAXK2];
    int t = threadIdx.x;
    int K2 = 4 * NBD;
    for (int i = t; i < K2; i += 512) cnt2[i] = 0;
    __syncthreads();

    int w0 = blockIdx.x * 2;
    // pass 1: histogram (gathers d only; warms d-windows in L2)
    for (int wi = 0; wi < 2; ++wi) {
        int w = w0 + wi;
        if (w >= NW) break;
        int c = gcnt1[w]; if (c > W1CAP) c = W1CAP;
        const unsigned* strm = recs1 + (size_t)w * W1CAP;
        for (int r = t; r < c; r += 512) {
            unsigned rec = strm[r];
            int idx = (int)(rec & 0x7FFFFFu);
            int st  = (int)(rec >> 23);
            int d = ei[idx];
            atomicAdd(&cnt2[st * NBD + (d >> 8)], 1);
        }
    }
    __syncthreads();
    for (int k = t; k < K2; k += 512) {
        int c = cnt2[k];
        cur[k] = c ? atomicAdd(&gcnt2[k], c) : 0;
    }
    __syncthreads();
    // pass 2: scatter (recs1 + d-window now L2-hot; s-window streamed once)
    for (int wi = 0; wi < 2; ++wi) {
        int w = w0 + wi;
        if (w >= NW) break;
        int c = gcnt1[w]; if (c > W1CAP) c = W1CAP;
        const unsigned* strm = recs1 + (size_t)w * W1CAP;
        for (int r = t; r < c; r += 512) {
            unsigned rec = strm[r];
            int idx = (int)(rec & 0x7FFFFFu);
            int st  = (int)(rec >> 23);
            int d = ei[idx];
            int s = ei[(size_t)ne + idx];
            int key = st * NBD + (d >> 8);
            int pos = atomicAdd(&cur[key], 1);
            unsigned r2 = ((unsigned)(d & 255) << 20) | (unsigned)s;
            if (pos < CAPB)
                __builtin_nontemporal_store(r2, &recs2[(size_t)key * CAPB + pos]);
            else {
                int o = atomicAdd(ovf2_cnt, 1);
                if (o < OVFN) ovf2[o] = make_int2((st << 18) | d, s);
            }
        }
    }
}

// ---------------- aggregate via in-LDS counting sort, register sums --------
// h_next[i] = h[i] + deg*(Wa.x_i + b) + Wb * sum_src x_src  ; NO fp atomics
// FINAL: also computes out = h_next @ w_out.T + b_out and skips h_next write.
template<bool FINAL>
__global__ __launch_bounds__(512) void k_agg2(const float* __restrict__ h_cur,
                                              float* __restrict__ h_next,
                                              const int* __restrict__ gcnt2_st,
                                              const unsigned* __restrict__ recs2_st,
                                              const float* __restrict__ w_mp,
                                              const float* __restrict__ b_mp,
                                              const float* __restrict__ w_out,
                                              const float* __restrict__ b_out,
                                              float* __restrict__ out, int n) {
    __shared__ unsigned srt[CAPB];      // records sorted by dl
    __shared__ int cnts[256];           // histogram, then cursor
    __shared__ int sc[256];             // scan scratch
    __shared__ int offs[257];           // exclusive offsets
    __shared__ float part[256 * 10];    // partner partial sums
    __shared__ float Wa[100], Wb[100], Bm[10];
    __shared__ float Wo[100], Bo[10];
    int t = threadIdx.x;
    if (t < 100) {
        int k = t / 10, j = t - k * 10;
        float w1 = w_mp[k * 20 + j];
        float w2 = w_mp[k * 20 + 10 + j];
        Wa[t] = w1 - w2; Wb[t] = w2;
        if (FINAL) Wo[t] = w_out[t];
    }
    if (t < 10) { Bm[t] = b_mp[t]; if (FINAL) Bo[t] = b_out[t]; }
    if (t < 256) cnts[t] = 0;
    __syncthreads();

    int bkt = blockIdx.x;
    int cnt = gcnt2_st[bkt];
    if (cnt > CAPB) cnt = CAPB;
    const unsigned* strm = recs2_st + (size_t)bkt * CAPB;

    // pass A: stage to registers + histogram
    unsigned myrec[(CAPB + 511) / 512];
    int nm = 0;
    for (int r = t; r < cnt; r += 512) {
        unsigned rec = strm[r];
        myrec[nm++] = rec;
        atomicAdd(&cnts[rec >> 20], 1);
    }
    __syncthreads();

    // exclusive scan of cnts -> offs
    if (t < 256) sc[t] = cnts[t];
    __syncthreads();
    for (int off = 1; off < 256; off <<= 1) {
        int v = (t < 256 && t >= off) ? sc[t - off] : 0;
        __syncthreads();
        if (t < 256) sc[t] += v;
        __syncthreads();
    }
    if (t < 256) offs[t + 1] = sc[t];
    if (t == 0) offs[0] = 0;
    __syncthreads();
    if (t < 256) cnts[t] = offs[t];     // cursor
    __syncthreads();

    // pass B: scatter into sorted order
    for (int q = 0; q < nm; ++q) {
        unsigned rec = myrec[q];
        int pos = atomicAdd(&cnts[rec >> 20], 1);
        srt[pos] = rec;
    }
    __syncthreads();

    // per-node gather-sum: 2 threads per node
    int node = t & 255, half = t >> 8;
    int b0 = offs[node], m = offs[node + 1] - b0;
    float S[10] = {0,0,0,0,0,0,0,0,0,0};
    for (int p = b0 + half; p < b0 + m; p += 2) {
        int s = (int)(srt[p] & 0xFFFFFu);
        const float* pj = h_cur + (size_t)s * 16;
        float4 a0 = *(const float4*)(pj);
        float4 a1 = *(const float4*)(pj + 4);
        float2 a2 = *(const float2*)(pj + 8);
        S[0] += a0.x; S[1] += a0.y; S[2] += a0.z; S[3] += a0.w;
        S[4] += a1.x; S[5] += a1.y; S[6] += a1.z; S[7] += a1.w;
        S[8] += a2.x; S[9] += a2.y;
    }
    if (half == 1) {
        #pragma unroll
        for (int j = 0; j < 10; ++j) part[node * 10 + j] = S[j];
    }
    __syncthreads();
    if (half == 0) {
        int i = bkt * 256 + node;
        if (i < n) {
            #pragma unroll
            for (int j = 0; j < 10; ++j) S[j] += part[node * 10 + j];
            const float* pi = h_cur + (size_t)i * 16;
            float4 x0 = *(const float4*)(pi);
            float4 x1 = *(const float4*)(pi + 4);
            float2 x2 = *(const float2*)(pi + 8);
            float xi[10] = {x0.x, x0.y, x0.z, x0.w, x1.x, x1.y, x1.z, x1.w, x2.x, x2.y};
            float deg = (float)m;
            float o[10];
            #pragma unroll
            for (int k = 0; k < 10; ++k) {
                float ma = Bm[k];
                float mb = 0.0f;
                #pragma unroll
                for (int j = 0; j < 10; ++j) {
                    ma += Wa[k * 10 + j] * xi[j];
                    mb += Wb[k * 10 + j] * S[j];
                }
                o[k] = xi[k] + deg * ma + mb;
            }
            if (FINAL) {
                float q2[10];
                #pragma unroll
                for (int k = 0; k < 10; ++k) {
                    float m2 = Bo[k];
                    #pragma unroll
                    for (int j = 0; j < 10; ++j) m2 += Wo[k * 10 + j] * o[j];
                    q2[k] = m2;
                }
                float* po = out + (size_t)i * 10;
                *(float2*)(po)     = make_float2(q2[0], q2[1]);
                *(float2*)(po + 2) = make_float2(q2[2], q2[3]);
                *(float2*)(po + 4) = make_float2(q2[4], q2[5]);
                *(float2*)(po + 6) = make_float2(q2[6], q2[7]);
                *(float2*)(po + 8) = make_float2(q2[8], q2[9]);
            } else {
                float* po = h_next + (size_t)i * 16;
                *(float4*)(po)     = make_float4(o[0], o[1], o[2], o[3]);
                *(float4*)(po + 4) = make_float4(o[4], o[5], o[6], o[7]);
                *(float2*)(po + 8) = make_float2(o[8], o[9]);
            }
        }
    }
}

// ---------------- overflow fix-up (expected zero entries) -------------------
__global__ void k_fix(const float* __restrict__ h_cur, float* __restrict__ h_next,
                      const int* __restrict__ ei, int ne,
                      const int* __restrict__ ovf1_cnt, const unsigned* __restrict__ ovf1,
                      const int* __restrict__ ovf2_cnt, const int2* __restrict__ ovf2,
                      const float* __restrict__ w_mp, const float* __restrict__ b_mp,
                      int st) {
    __shared__ float Wa[100], Wb[100], Bm[10];
    int t = threadIdx.x;
    if (t < 100) {
        int k = t / 10, j = t - k * 10;
        float w1 = w_mp[k * 20 + j];
        float w2 = w_mp[k * 20 + 10 + j];
        Wa[t] = w1 - w2; Wb[t] = w2;
    }
    if (t < 10) Bm[t] = b_mp[t];
    __syncthreads();
    int c1 = *ovf1_cnt; if (c1 > OVFN) c1 = OVFN;
    int c2 = *ovf2_cnt; if (c2 > OVFN) c2 = OVFN;
    int gs = gridDim.x * blockDim.x;
    for (int i = blockIdx.x * blockDim.x + t; i < c1 + c2; i += gs) {
        int d, s;
        if (i < c1) {
            unsigned v = ovf1[i];
            if ((int)(v >> 23) != st) continue;
            int idx = (int)(v & 0x7FFFFFu);
            d = ei[idx]; s = ei[(size_t)ne + idx];
        } else {
            int2 p = ovf2[i - c1];
            if ((p.x >> 18) != st) continue;
            d = p.x & 0x3FFFF; s = p.y;
        }
        const float* pi = h_cur + (size_t)d * 16;
        const float* pj = h_cur + (size_t)s * 16;
        float xi[10], xj[10];
        #pragma unroll
        for (int j = 0; j < 10; ++j) { xi[j] = pi[j]; xj[j] = pj[j]; }
        float* po = h_next + (size_t)d * 16;
        #pragma unroll
        for (int k = 0; k < 10; ++k) {
            float m = Bm[k];
            #pragma unroll
            for (int j = 0; j < 10; ++j) m += Wa[k * 10 + j] * xi[j] + Wb[k * 10 + j] * xj[j];
            atomicAdd(po + k, m);
        }
    }
}

// final-step overflow: project the missing message through w_out into out
__global__ void k_fix_final(const float* __restrict__ h_cur, float* __restrict__ out,
                            const int* __restrict__ ei, int ne,
                            const int* __restrict__ ovf1_cnt, const unsigned* __restrict__ ovf1,
                            const int* __restrict__ ovf2_cnt, const int2* __restrict__ ovf2,
                            const float* __restrict__ w_mp, const float* __restrict__ b_mp,
                            const float* __restrict__ w_out, int st) {
    __shared__ float Wa[100], Wb[100], Bm[10], Wo[100];
    int t = threadIdx.x;
    if (t < 100) {
        int k = t / 10, j = t - k * 10;
        float w1 = w_mp[k * 20 + j];
        float w2 = w_mp[k * 20 + 10 + j];
        Wa[t] = w1 - w2; Wb[t] = w2;
        Wo[t] = w_out[t];
    }
    if (t < 10) Bm[t] = b_mp[t];
    __syncthreads();
    int c1 = *ovf1_cnt; if (c1 > OVFN) c1 = OVFN;
    int c2 = *ovf2_cnt; if (c2 > OVFN) c2 = OVFN;
    int gs = gridDim.x * blockDim.x;
    for (int i = blockIdx.x * blockDim.x + t; i < c1 + c2; i += gs) {
        int d, s;
        if (i < c1) {
            unsigned v = ovf1[i];
            if ((int)(v >> 23) != st) continue;
            int idx = (int)(v & 0x7FFFFFu);
            d = ei[idx]; s = ei[(size_t)ne + idx];
        } else {
            int2 p = ovf2[i - c1];
            if ((p.x >> 18) != st) continue;
            d = p.x & 0x3FFFF; s = p.y;
        }
        const float* pi = h_cur + (size_t)d * 16;
        const float* pj = h_cur + (size_t)s * 16;
        float xi[10], xj[10];
        #pragma unroll
        for (int j = 0; j < 10; ++j) { xi[j] = pi[j]; xj[j] = pj[j]; }
        float dm[10];
        #pragma unroll
        for (int k = 0; k < 10; ++k) {
            float m = Bm[k];
            #pragma unroll
            for (int j = 0; j < 10; ++j) m += Wa[k * 10 + j] * xi[j] + Wb[k * 10 + j] * xj[j];
            dm[k] = m;
        }
        float* po = out + (size_t)d * 10;
        #pragma unroll
        for (int q = 0; q < 10; ++q) {
            float m = 0.0f;
            #pragma unroll
            for (int k = 0; k < 10; ++k) m += Wo[q * 10 + k] * dm[k];
            atomicAdd(po + q, m);
        }
    }
}

// =================== tiny-ws atomic fallback ================================

__global__ void k_init10(const float* __restrict__ x, float* __restrict__ h, int n10) {
    int gs = gridDim.x * blockDim.x;
    for (int i = blockIdx.x * blockDim.x + threadIdx.x; i < n10; i += gs) h[i] = x[i];
}
__global__ void k_copy4(const float4* __restrict__ src, float4* __restrict__ dst, int n4) {
    int gs = gridDim.x * blockDim.x;
    for (int i = blockIdx.x * blockDim.x + threadIdx.x; i < n4; i += gs) dst[i] = src[i];
}
__global__ void k_edge_step10(const float* __restrict__ h_cur, float* __restrict__ h_next,
                              const int* __restrict__ edge_index, const int* __restrict__ order,
                              const float* __restrict__ w_mp, const float* __restrict__ b_mp,
                              int epo, int ne) {
    __shared__ float Wc[200]; __shared__ float Bc[10];
    int t = threadIdx.x;
    if (t < 200) {
        int k = t / 20, j = t - k * 20;
        float w = w_mp[t];
        Wc[t] = (j < 10) ? (w - w_mp[k * 20 + j + 10]) : w;
    }
    if (t < 10) Bc[t] = b_mp[t];
    __syncthreads();
    int gs = gridDim.x * blockDim.x;
    for (int e = blockIdx.x * blockDim.x + t; e < epo; e += gs) {
        int idx = order[e];
        int dst = edge_index[idx];
        int src = edge_index[(size_t)ne + idx];
        const float* pi = h_cur + (size_t)dst * 10;
        const float* pj = h_cur + (size_t)src * 10;
        float xi[10], xj[10];
        #pragma unroll
        for (int j = 0; j < 10; ++j) { xi[j] = pi[j]; xj[j] = pj[j]; }
        float* po = h_next + (size_t)dst * 10;
        #pragma unroll
        for (int k = 0; k < 10; ++k) {
            float m = Bc[k];
            #pragma unroll
            for (int j = 0; j < 10; ++j) m += Wc[k * 20 + j] * xi[j] + Wc[k * 20 + 10 + j] * xj[j];
            atomicAdd(po + k, m);
        }
    }
}
__global__ void k_out10(const float* __restrict__ h, const float* __restrict__ w_out,
                        const float* __restrict__ b_out, float* __restrict__ out, int n) {
    __shared__ float W[100]; __shared__ float B[10];
    int t = threadIdx.x;
    if (t < 100) W[t] = w_out[t];
    if (t < 10)  B[t] = b_out[t];
    __syncthreads();
    int gs = gridDim.x * blockDim.x;
    for (int i = blockIdx.x * blockDim.x + t; i < n; i += gs) {
        float xi[10];
        #pragma unroll
        for (int j = 0; j < 10; ++j) xi[j] = h[(size_t)i * 10 + j];
        #pragma unroll
        for (int k = 0; k < 10; ++k) {
            float m = B[k];
            #pragma unroll
            for (int j = 0; j < 10; ++j) m += W[k * 10 + j] * xi[j];
            out[(size_t)i * 10 + k] = m;
        }
    }
}

// =================== launcher ===================

extern "C" void kernel_launch(void* const* d_in, const int* in_sizes, int n_in,
                              void* d_out, int out_size, void* d_ws, size_t ws_size,
                              hipStream_t stream) {
    const float* x      = (const float*)d_in[0];
    const float* w_mp   = (const float*)d_in[1];
    const float* b_mp   = (const float*)d_in[2];
    const float* w_out  = (const float*)d_in[3];
    const float* b_out  = (const float*)d_in[4];
    const int*   edge_i = (const int*)d_in[5];
    const int*   orders = (const int*)d_in[6];

    int n  = in_sizes[0] / 10;        // 100000
    int ne = in_sizes[5] / 2;         // 6400000
    const int n_orders = 4;
    int epo = in_sizes[6] / n_orders; // 1600000
    int total = n_orders * epo;

    float* out = (float*)d_out;

    int NBD = (n + 255) >> 8;                    // 391 dst buckets
    int NW  = (ne + (1 << WBITS) - 1) >> WBITS;  // 782 idx windows

    // workspace layout (4B elements)
    size_t off_hA    = 0;
    size_t off_hB    = off_hA + (size_t)n * 16;
    size_t off_recs1 = off_hB + (size_t)n * 16;
    size_t off_recs2 = off_recs1 + (size_t)NW * W1CAP;
    size_t off_ovf2  = off_recs2 + (size_t)4 * NBD * CAPB;   // even offset (int2)
    size_t off_ovf1  = off_ovf2 + (size_t)2 * OVFN;
    size_t off_gcnt1 = off_ovf1 + OVFN;
    size_t off_gcnt2 = off_gcnt1 + NW;
    size_t off_cnts  = off_gcnt2 + (size_t)4 * NBD;          // [0]=ovf1, [1]=ovf2
    size_t need      = (off_cnts + 2) * 4;

    bool ok = (ws_size >= need) && (NW <= MAXNW) && (NBD <= MAXNBD) &&
              (4 * NBD <= MAXK2) && (ne <= (1 << 23)) && (n < (1 << 17));

    if (!ok) {
        // tiny-ws atomic fallback (8 MB)
        float* hA = (float*)d_ws;
        float* hB = hA + (size_t)n * 10;
        int n10 = n * 10;
        hipLaunchKernelGGL(k_init10, dim3(min((n10 + BLK - 1) / BLK, 2048)), dim3(BLK), 0, stream,
                           x, hA, n10);
        int n4 = n10 / 4;
        float* cur = hA; float* nxt = hB;
        int gb_edge = min((epo + BLK - 1) / BLK, 6400);
        for (int s = 0; s < n_orders; ++s) {
            hipLaunchKernelGGL(k_copy4, dim3(min((n4 + BLK - 1) / BLK, 2048)), dim3(BLK), 0, stream,
                               (const float4*)cur, (float4*)nxt, n4);
            hipLaunchKernelGGL(k_edge_step10, dim3(gb_edge), dim3(BLK), 0, stream,
                               cur, nxt, edge_i, orders + (size_t)s * epo, w_mp, b_mp, epo, ne);
            float* t2 = cur; cur = nxt; nxt = t2;
        }
        hipLaunchKernelGGL(k_out10, dim3(min((n + BLK - 1) / BLK, 2048)), dim3(BLK), 0, stream,
                           cur, w_out, b_out, out, n);
        return;
    }

    float*    hA      = (float*)d_ws;
    float*    hB      = (float*)d_ws + off_hB;
    unsigned* recs1   = (unsigned*)d_ws + off_recs1;
    unsigned* recs2   = (unsigned*)d_ws + off_recs2;
    int2*     ovf2    = (int2*)((int*)d_ws + off_ovf2);
    unsigned* ovf1    = (unsigned*)d_ws + off_ovf1;
    int*      gcnt1   = (int*)d_ws + off_gcnt1;
    int*      gcnt2   = (int*)d_ws + off_gcnt2;
    int*      ovfcnts = (int*)d_ws + off_cnts;

    // zero gcnt1 + gcnt2 + ovf counters (contiguous)
    hipMemsetAsync(gcnt1, 0, ((size_t)NW + (size_t)4 * NBD + 2) * sizeof(int), stream);

    int gb_init = min((n * 16 + BLK - 1) / BLK, 2048);
    hipLaunchKernelGGL(k_init_h, dim3(gb_init), dim3(BLK), 0, stream, x, hA, n);

    int gbA = (total + 512 * IPTA - 1) / (512 * IPTA);   // 391
    hipLaunchKernelGGL(k_win, dim3(gbA), dim3(512), 0, stream,
                       orders, total, epo, NW, gcnt1, recs1, ovfcnts + 0, ovf1);

    int gbB = (NW + 1) / 2;                              // 391
    hipLaunchKernelGGL(k_bin2, dim3(gbB), dim3(512), 0, stream,
                       edge_i, ne, gcnt1, recs1, NW, NBD,
                       gcnt2, recs2, ovfcnts + 1, ovf2);

    float* cur = hA; float* nxt = hB;
    for (int s = 0; s < n_orders; ++s) {
        bool fin = (s == n_orders - 1);
        if (fin) {
            hipLaunchKernelGGL((k_agg2<true>), dim3(NBD), dim3(512), 0, stream,
                               cur, nxt, gcnt2 + (size_t)s * NBD,
                               recs2 + (size_t)s * NBD * CAPB, w_mp, b_mp,
                               w_out, b_out, out, n);
            hipLaunchKernelGGL(k_fix_final, dim3(8), dim3(256), 0, stream,
                               cur, out, edge_i, ne,
                               ovfcnts + 0, ovf1, ovfcnts + 1, ovf2,
                               w_mp, b_mp, w_out, s);
        } else {
            hipLaunchKernelGGL((k_agg2<false>), dim3(NBD), dim3(512), 0, stream,
                               cur, nxt, gcnt2 + (size_t)s * NBD,
                               recs2 + (size_t)s * NBD * CAPB, w_mp, b_mp,
                               w_out, b_out, out, n);
            hipLaunchKernelGGL(k_fix, dim3(8), dim3(256), 0, stream,
                               cur, nxt, edge_i, ne,
                               ovfcnts + 0, ovf1, ovfcnts + 1, ovf2,
                               w_mp, b_mp, s);
            float* t2 = cur; cur = nxt; nxt = t2;
        }
    }
}

// Round 8
// 286.661 us; speedup vs baseline: 2.1487x; 2.1487x over previous
//
#include <hip/hip_runtime.h>

#define BLK 256
#define CAPB 4608         // per-(step,dst-bucket) stream cap: mean 4092, sd 64 (+8 sigma)
#define MAXNBD 512
#define MAXK2 2048
#define OVFN 65536
#define WBITS 13          // idx-window = 8192 edges (32KB per ei half)
#define W1CAP 8928        // window stream cap: mean 8184, sd ~90 (+8 sigma)
#define MAXNW 1024
#define IPTA 32           // k_win: 512 thr * 32 = 16384 entries/block
#define IPT2 18           // k_bin2: 512 thr * 18 = 9216 >= W1CAP

// ---------------- init: copy compact x (n,10) into strided h (n,16) --------
__global__ void k_init_h(const float* __restrict__ x, float* __restrict__ h, int n) {
    int total = n * 16;
    int gs = gridDim.x * blockDim.x;
    for (int i = blockIdx.x * blockDim.x + threadIdx.x; i < total; i += gs) {
        int row = i >> 4, col = i & 15;
        h[i] = (col < 10) ? x[row * 10 + col] : 0.0f;
    }
}

// ---------------- pass A: bin order entries by idx-window (no gathers) -----
// recs1[w][pos] = (st<<23)|idx
__global__ __launch_bounds__(512) void k_win(const int* __restrict__ orders,
                                             int total, int epo, int NW,
                                             int* __restrict__ gcnt1,
                                             unsigned* __restrict__ recs1,
                                             int* __restrict__ ovf1_cnt,
                                             unsigned* __restrict__ ovf1) {
    __shared__ int bcnt[MAXNW];
    __shared__ int gbase[MAXNW];
    int t = threadIdx.x;
    for (int i = t; i < NW; i += 512) bcnt[i] = 0;
    __syncthreads();

    size_t base = (size_t)blockIdx.x * (512 * IPTA);
    int st0 = (int)(base / (size_t)epo);
    size_t b1 = (size_t)(st0 + 1) * (size_t)epo;   // block spans <= one step boundary

    unsigned recr[IPTA]; int rr[IPTA];
    #pragma unroll
    for (int q = 0; q < IPTA; ++q) {
        size_t g = base + (size_t)q * 512 + t;
        recr[q] = 0xFFFFFFFFu; rr[q] = 0;
        if (g < (size_t)total) {
            int idx = orders[g];
            int st = (g >= b1) ? (st0 + 1) : st0;
            recr[q] = ((unsigned)st << 23) | (unsigned)idx;
            rr[q] = atomicAdd(&bcnt[idx >> WBITS], 1);
        }
    }
    __syncthreads();
    for (int k = t; k < NW; k += 512) {
        int c = bcnt[k];
        gbase[k] = c ? atomicAdd(&gcnt1[k], c) : 0;
    }
    __syncthreads();
    #pragma unroll
    for (int q = 0; q < IPTA; ++q) {
        if (recr[q] != 0xFFFFFFFFu) {
            int idx = (int)(recr[q] & 0x7FFFFFu);
            int key = idx >> WBITS;
            int pos = gbase[key] + rr[q];
            if (pos < W1CAP)
                recs1[(size_t)key * W1CAP + pos] = recr[q];
            else {
                int o = atomicAdd(ovf1_cnt, 1);
                if (o < OVFN) ovf1[o] = recr[q];
            }
        }
    }
}

// ---------------- pass B: resolve (d,s) in L2 window, bin by (st, d>>8) ----
// 1 window/block, single pass, static unroll: all loads independent.
__global__ __launch_bounds__(512) void k_bin2(const int* __restrict__ ei, int ne,
                                              const int* __restrict__ gcnt1,
                                              const unsigned* __restrict__ recs1,
                                              int NW, int NBD,
                                              int* __restrict__ gcnt2,
                                              unsigned* __restrict__ recs2,
                                              int* __restrict__ ovf2_cnt,
                                              int2* __restrict__ ovf2) {
    __shared__ int cnt2[MAXK2];
    __shared__ int gbase[MAXK2];
    int t = threadIdx.x;
    int K2 = 4 * NBD;
    for (int i = t; i < K2; i += 512) cnt2[i] = 0;
    __syncthreads();

    int w = blockIdx.x;
    int c = gcnt1[w]; if (c > W1CAP) c = W1CAP;
    const unsigned* strm = recs1 + (size_t)w * W1CAP;

    // 1) independent stream loads
    unsigned recr[IPT2];
    #pragma unroll
    for (int q = 0; q < IPT2; ++q) {
        int r = q * 512 + t;
        recr[q] = (r < c) ? strm[r] : 0xFFFFFFFFu;
    }
    // 2) independent window gathers (32KB windows, L2/L1-hot after first touch)
    int dv[IPT2], sv[IPT2];
    #pragma unroll
    for (int q = 0; q < IPT2; ++q) {
        dv[q] = 0; sv[q] = 0;
        if (recr[q] != 0xFFFFFFFFu) {
            int idx = (int)(recr[q] & 0x7FFFFFu);
            dv[q] = ei[idx];
            sv[q] = ei[(size_t)ne + idx];
        }
    }
    // 3) LDS rank
    int meta[IPT2];
    #pragma unroll
    for (int q = 0; q < IPT2; ++q) {
        meta[q] = -1;
        if (recr[q] != 0xFFFFFFFFu) {
            int st = (int)(recr[q] >> 23);
            int key = st * NBD + (dv[q] >> 8);
            int rk = atomicAdd(&cnt2[key], 1);     // < W1CAP < 16384
            meta[q] = (key << 14) | rk;
        }
    }
    __syncthreads();
    // 4) one global reservation per touched key
    for (int k = t; k < K2; k += 512) {
        int cc = cnt2[k];
        gbase[k] = cc ? atomicAdd(&gcnt2[k], cc) : 0;
    }
    __syncthreads();
    // 5) scatter (plain stores: recs2 is re-read by k_agg2 — keep in L2)
    #pragma unroll
    for (int q = 0; q < IPT2; ++q) {
        if (meta[q] >= 0) {
            int key = meta[q] >> 14, rk = meta[q] & 16383;
            int pos = gbase[key] + rk;
            unsigned r2 = ((unsigned)(dv[q] & 255) << 20) | (unsigned)sv[q];
            if (pos < CAPB)
                recs2[(size_t)key * CAPB + pos] = r2;
            else {
                int o = atomicAdd(ovf2_cnt, 1);
                if (o < OVFN) {
                    int st = (int)(recr[q] >> 23);
                    ovf2[o] = make_int2((st << 18) | dv[q], sv[q]);
                }
            }
        }
    }
}

// ---------------- aggregate via in-LDS counting sort, register sums --------
// h_next[i] = h[i] + deg*(Wa.x_i + b) + Wb * sum_src x_src  ; NO fp atomics
// FINAL: also computes out = h_next @ w_out.T + b_out and skips h_next write.
#define IPTG ((CAPB + 511) / 512)    // 9
template<bool FINAL>
__global__ __launch_bounds__(512) void k_agg2(const float* __restrict__ h_cur,
                                              float* __restrict__ h_next,
                                              const int* __restrict__ gcnt2_st,
                                              const unsigned* __restrict__ recs2_st,
                                              const float* __restrict__ w_mp,
                                              const float* __restrict__ b_mp,
                                              const float* __restrict__ w_out,
                                              const float* __restrict__ b_out,
                                              float* __restrict__ out, int n) {
    __shared__ unsigned srt[CAPB];      // records sorted by dl
    __shared__ int cnts[256];           // histogram, then cursor
    __shared__ int sc[256];             // scan scratch
    __shared__ int offs[257];           // exclusive offsets
    __shared__ float part[256 * 10];    // partner partial sums
    __shared__ float Wa[100], Wb[100], Bm[10];
    __shared__ float Wo[100], Bo[10];
    int t = threadIdx.x;
    if (t < 100) {
        int k = t / 10, j = t - k * 10;
        float w1 = w_mp[k * 20 + j];
        float w2 = w_mp[k * 20 + 10 + j];
        Wa[t] = w1 - w2; Wb[t] = w2;
        if (FINAL) Wo[t] = w_out[t];
    }
    if (t < 10) { Bm[t] = b_mp[t]; if (FINAL) Bo[t] = b_out[t]; }
    if (t < 256) cnts[t] = 0;
    __syncthreads();

    int bkt = blockIdx.x;
    int cnt = gcnt2_st[bkt];
    if (cnt > CAPB) cnt = CAPB;
    const unsigned* strm = recs2_st + (size_t)bkt * CAPB;

    // pass A: stage to registers (static indices) + histogram
    unsigned myrec[IPTG];
    #pragma unroll
    for (int q = 0; q < IPTG; ++q) {
        int r = q * 512 + t;
        myrec[q] = 0xFFFFFFFFu;
        if (r < cnt) {
            unsigned rec = strm[r];
            myrec[q] = rec;
            atomicAdd(&cnts[rec >> 20], 1);
        }
    }
    __syncthreads();

    // exclusive scan of cnts -> offs
    if (t < 256) sc[t] = cnts[t];
    __syncthreads();
    for (int off = 1; off < 256; off <<= 1) {
        int v = (t < 256 && t >= off) ? sc[t - off] : 0;
        __syncthreads();
        if (t < 256) sc[t] += v;
        __syncthreads();
    }
    if (t < 256) offs[t + 1] = sc[t];
    if (t == 0) offs[0] = 0;
    __syncthreads();
    if (t < 256) cnts[t] = offs[t];     // cursor
    __syncthreads();

    // pass B: scatter into sorted order
    #pragma unroll
    for (int q = 0; q < IPTG; ++q) {
        if (myrec[q] != 0xFFFFFFFFu) {
            int pos = atomicAdd(&cnts[myrec[q] >> 20], 1);
            srt[pos] = myrec[q];
        }
    }
    __syncthreads();

    // per-node gather-sum: 2 threads per node
    int node = t & 255, half = t >> 8;
    int b0 = offs[node], m = offs[node + 1] - b0;
    float S[10] = {0,0,0,0,0,0,0,0,0,0};
    for (int p = b0 + half; p < b0 + m; p += 2) {
        int s = (int)(srt[p] & 0xFFFFFu);
        const float* pj = h_cur + (size_t)s * 16;
        float4 a0 = *(const float4*)(pj);
        float4 a1 = *(const float4*)(pj + 4);
        float2 a2 = *(const float2*)(pj + 8);
        S[0] += a0.x; S[1] += a0.y; S[2] += a0.z; S[3] += a0.w;
        S[4] += a1.x; S[5] += a1.y; S[6] += a1.z; S[7] += a1.w;
        S[8] += a2.x; S[9] += a2.y;
    }
    if (half == 1) {
        #pragma unroll
        for (int j = 0; j < 10; ++j) part[node * 10 + j] = S[j];
    }
    __syncthreads();
    if (half == 0) {
        int i = bkt * 256 + node;
        if (i < n) {
            #pragma unroll
            for (int j = 0; j < 10; ++j) S[j] += part[node * 10 + j];
            const float* pi = h_cur + (size_t)i * 16;
            float4 x0 = *(const float4*)(pi);
            float4 x1 = *(const float4*)(pi + 4);
            float2 x2 = *(const float2*)(pi + 8);
            float xi[10] = {x0.x, x0.y, x0.z, x0.w, x1.x, x1.y, x1.z, x1.w, x2.x, x2.y};
            float deg = (float)m;
            float o[10];
            #pragma unroll
            for (int k = 0; k < 10; ++k) {
                float ma = Bm[k];
                float mb = 0.0f;
                #pragma unroll
                for (int j = 0; j < 10; ++j) {
                    ma += Wa[k * 10 + j] * xi[j];
                    mb += Wb[k * 10 + j] * S[j];
                }
                o[k] = xi[k] + deg * ma + mb;
            }
            if (FINAL) {
                float q2[10];
                #pragma unroll
                for (int k = 0; k < 10; ++k) {
                    float m2 = Bo[k];
                    #pragma unroll
                    for (int j = 0; j < 10; ++j) m2 += Wo[k * 10 + j] * o[j];
                    q2[k] = m2;
                }
                float* po = out + (size_t)i * 10;
                *(float2*)(po)     = make_float2(q2[0], q2[1]);
                *(float2*)(po + 2) = make_float2(q2[2], q2[3]);
                *(float2*)(po + 4) = make_float2(q2[4], q2[5]);
                *(float2*)(po + 6) = make_float2(q2[6], q2[7]);
                *(float2*)(po + 8) = make_float2(q2[8], q2[9]);
            } else {
                float* po = h_next + (size_t)i * 16;
                *(float4*)(po)     = make_float4(o[0], o[1], o[2], o[3]);
                *(float4*)(po + 4) = make_float4(o[4], o[5], o[6], o[7]);
                *(float2*)(po + 8) = make_float2(o[8], o[9]);
            }
        }
    }
}

// ---------------- overflow fix-up (expected zero entries) -------------------
__global__ void k_fix(const float* __restrict__ h_cur, float* __restrict__ h_next,
                      const int* __restrict__ ei, int ne,
                      const int* __restrict__ ovf1_cnt, const unsigned* __restrict__ ovf1,
                      const int* __restrict__ ovf2_cnt, const int2* __restrict__ ovf2,
                      const float* __restrict__ w_mp, const float* __restrict__ b_mp,
                      int st) {
    __shared__ float Wa[100], Wb[100], Bm[10];
    int t = threadIdx.x;
    if (t < 100) {
        int k = t / 10, j = t - k * 10;
        float w1 = w_mp[k * 20 + j];
        float w2 = w_mp[k * 20 + 10 + j];
        Wa[t] = w1 - w2; Wb[t] = w2;
    }
    if (t < 10) Bm[t] = b_mp[t];
    __syncthreads();
    int c1 = *ovf1_cnt; if (c1 > OVFN) c1 = OVFN;
    int c2 = *ovf2_cnt; if (c2 > OVFN) c2 = OVFN;
    int gs = gridDim.x * blockDim.x;
    for (int i = blockIdx.x * blockDim.x + t; i < c1 + c2; i += gs) {
        int d, s;
        if (i < c1) {
            unsigned v = ovf1[i];
            if ((int)(v >> 23) != st) continue;
            int idx = (int)(v & 0x7FFFFFu);
            d = ei[idx]; s = ei[(size_t)ne + idx];
        } else {
            int2 p = ovf2[i - c1];
            if ((p.x >> 18) != st) continue;
            d = p.x & 0x3FFFF; s = p.y;
        }
        const float* pi = h_cur + (size_t)d * 16;
        const float* pj = h_cur + (size_t)s * 16;
        float xi[10], xj[10];
        #pragma unroll
        for (int j = 0; j < 10; ++j) { xi[j] = pi[j]; xj[j] = pj[j]; }
        float* po = h_next + (size_t)d * 16;
        #pragma unroll
        for (int k = 0; k < 10; ++k) {
            float m = Bm[k];
            #pragma unroll
            for (int j = 0; j < 10; ++j) m += Wa[k * 10 + j] * xi[j] + Wb[k * 10 + j] * xj[j];
            atomicAdd(po + k, m);
        }
    }
}

// final-step overflow: project the missing message through w_out into out
__global__ void k_fix_final(const float* __restrict__ h_cur, float* __restrict__ out,
                            const int* __restrict__ ei, int ne,
                            const int* __restrict__ ovf1_cnt, const unsigned* __restrict__ ovf1,
                            const int* __restrict__ ovf2_cnt, const int2* __restrict__ ovf2,
                            const float* __restrict__ w_mp, const float* __restrict__ b_mp,
                            const float* __restrict__ w_out, int st) {
    __shared__ float Wa[100], Wb[100], Bm[10], Wo[100];
    int t = threadIdx.x;
    if (t < 100) {
        int k = t / 10, j = t - k * 10;
        float w1 = w_mp[k * 20 + j];
        float w2 = w_mp[k * 20 + 10 + j];
        Wa[t] = w1 - w2; Wb[t] = w2;
        Wo[t] = w_out[t];
    }
    if (t < 10) Bm[t] = b_mp[t];
    __syncthreads();
    int c1 = *ovf1_cnt; if (c1 > OVFN) c1 = OVFN;
    int c2 = *ovf2_cnt; if (c2 > OVFN) c2 = OVFN;
    int gs = gridDim.x * blockDim.x;
    for (int i = blockIdx.x * blockDim.x + t; i < c1 + c2; i += gs) {
        int d, s;
        if (i < c1) {
            unsigned v = ovf1[i];
            if ((int)(v >> 23) != st) continue;
            int idx = (int)(v & 0x7FFFFFu);
            d = ei[idx]; s = ei[(size_t)ne + idx];
        } else {
            int2 p = ovf2[i - c1];
            if ((p.x >> 18) != st) continue;
            d = p.x & 0x3FFFF; s = p.y;
        }
        const float* pi = h_cur + (size_t)d * 16;
        const float* pj = h_cur + (size_t)s * 16;
        float xi[10], xj[10];
        #pragma unroll
        for (int j = 0; j < 10; ++j) { xi[j] = pi[j]; xj[j] = pj[j]; }
        float dm[10];
        #pragma unroll
        for (int k = 0; k < 10; ++k) {
            float m = Bm[k];
            #pragma unroll
            for (int j = 0; j < 10; ++j) m += Wa[k * 10 + j] * xi[j] + Wb[k * 10 + j] * xj[j];
            dm[k] = m;
        }
        float* po = out + (size_t)d * 10;
        #pragma unroll
        for (int q = 0; q < 10; ++q) {
            float m = 0.0f;
            #pragma unroll
            for (int k = 0; k < 10; ++k) m += Wo[q * 10 + k] * dm[k];
            atomicAdd(po + q, m);
        }
    }
}

// =================== tiny-ws atomic fallback ================================

__global__ void k_init10(const float* __restrict__ x, float* __restrict__ h, int n10) {
    int gs = gridDim.x * blockDim.x;
    for (int i = blockIdx.x * blockDim.x + threadIdx.x; i < n10; i += gs) h[i] = x[i];
}
__global__ void k_copy4(const float4* __restrict__ src, float4* __restrict__ dst, int n4) {
    int gs = gridDim.x * blockDim.x;
    for (int i = blockIdx.x * blockDim.x + threadIdx.x; i < n4; i += gs) dst[i] = src[i];
}
__global__ void k_edge_step10(const float* __restrict__ h_cur, float* __restrict__ h_next,
                              const int* __restrict__ edge_index, const int* __restrict__ order,
                              const float* __restrict__ w_mp, const float* __restrict__ b_mp,
                              int epo, int ne) {
    __shared__ float Wc[200]; __shared__ float Bc[10];
    int t = threadIdx.x;
    if (t < 200) {
        int k = t / 20, j = t - k * 20;
        float w = w_mp[t];
        Wc[t] = (j < 10) ? (w - w_mp[k * 20 + j + 10]) : w;
    }
    if (t < 10) Bc[t] = b_mp[t];
    __syncthreads();
    int gs = gridDim.x * blockDim.x;
    for (int e = blockIdx.x * blockDim.x + t; e < epo; e += gs) {
        int idx = order[e];
        int dst = edge_index[idx];
        int src = edge_index[(size_t)ne + idx];
        const float* pi = h_cur + (size_t)dst * 10;
        const float* pj = h_cur + (size_t)src * 10;
        float xi[10], xj[10];
        #pragma unroll
        for (int j = 0; j < 10; ++j) { xi[j] = pi[j]; xj[j] = pj[j]; }
        float* po = h_next + (size_t)dst * 10;
        #pragma unroll
        for (int k = 0; k < 10; ++k) {
            float m = Bc[k];
            #pragma unroll
            for (int j = 0; j < 10; ++j) m += Wc[k * 20 + j] * xi[j] + Wc[k * 20 + 10 + j] * xj[j];
            atomicAdd(po + k, m);
        }
    }
}
__global__ void k_out10(const float* __restrict__ h, const float* __restrict__ w_out,
                        const float* __restrict__ b_out, float* __restrict__ out, int n) {
    __shared__ float W[100]; __shared__ float B[10];
    int t = threadIdx.x;
    if (t < 100) W[t] = w_out[t];
    if (t < 10)  B[t] = b_out[t];
    __syncthreads();
    int gs = gridDim.x * blockDim.x;
    for (int i = blockIdx.x * blockDim.x + t; i < n; i += gs) {
        float xi[10];
        #pragma unroll
        for (int j = 0; j < 10; ++j) xi[j] = h[(size_t)i * 10 + j];
        #pragma unroll
        for (int k = 0; k < 10; ++k) {
            float m = B[k];
            #pragma unroll
            for (int j = 0; j < 10; ++j) m += W[k * 10 + j] * xi[j];
            out[(size_t)i * 10 + k] = m;
        }
    }
}

// =================== launcher ===================

extern "C" void kernel_launch(void* const* d_in, const int* in_sizes, int n_in,
                              void* d_out, int out_size, void* d_ws, size_t ws_size,
                              hipStream_t stream) {
    const float* x      = (const float*)d_in[0];
    const float* w_mp   = (const float*)d_in[1];
    const float* b_mp   = (const float*)d_in[2];
    const float* w_out  = (const float*)d_in[3];
    const float* b_out  = (const float*)d_in[4];
    const int*   edge_i = (const int*)d_in[5];
    const int*   orders = (const int*)d_in[6];

    int n  = in_sizes[0] / 10;        // 100000
    int ne = in_sizes[5] / 2;         // 6400000
    const int n_orders = 4;
    int epo = in_sizes[6] / n_orders; // 1600000
    int total = n_orders * epo;

    float* out = (float*)d_out;

    int NBD = (n + 255) >> 8;                    // 391 dst buckets
    int NW  = (ne + (1 << WBITS) - 1) >> WBITS;  // 782 idx windows

    // workspace layout (4B elements)
    size_t off_hA    = 0;
    size_t off_hB    = off_hA + (size_t)n * 16;
    size_t off_recs1 = off_hB + (size_t)n * 16;
    size_t off_recs2 = off_recs1 + (size_t)NW * W1CAP;
    size_t off_ovf2  = off_recs2 + (size_t)4 * NBD * CAPB;   // even offset (int2)
    size_t off_ovf1  = off_ovf2 + (size_t)2 * OVFN;
    size_t off_gcnt1 = off_ovf1 + OVFN;
    size_t off_gcnt2 = off_gcnt1 + NW;
    size_t off_cnts  = off_gcnt2 + (size_t)4 * NBD;          // [0]=ovf1, [1]=ovf2
    size_t need      = (off_cnts + 2) * 4;

    bool ok = (ws_size >= need) && (NW <= MAXNW) && (NBD <= MAXNBD) &&
              (4 * NBD <= MAXK2) && (ne <= (1 << 23)) && (n < (1 << 17));

    if (!ok) {
        // tiny-ws atomic fallback (8 MB)
        float* hA = (float*)d_ws;
        float* hB = hA + (size_t)n * 10;
        int n10 = n * 10;
        hipLaunchKernelGGL(k_init10, dim3(min((n10 + BLK - 1) / BLK, 2048)), dim3(BLK), 0, stream,
                           x, hA, n10);
        int n4 = n10 / 4;
        float* cur = hA; float* nxt = hB;
        int gb_edge = min((epo + BLK - 1) / BLK, 6400);
        for (int s = 0; s < n_orders; ++s) {
            hipLaunchKernelGGL(k_copy4, dim3(min((n4 + BLK - 1) / BLK, 2048)), dim3(BLK), 0, stream,
                               (const float4*)cur, (float4*)nxt, n4);
            hipLaunchKernelGGL(k_edge_step10, dim3(gb_edge), dim3(BLK), 0, stream,
                               cur, nxt, edge_i, orders + (size_t)s * epo, w_mp, b_mp, epo, ne);
            float* t2 = cur; cur = nxt; nxt = t2;
        }
        hipLaunchKernelGGL(k_out10, dim3(min((n + BLK - 1) / BLK, 2048)), dim3(BLK), 0, stream,
                           cur, w_out, b_out, out, n);
        return;
    }

    float*    hA      = (float*)d_ws;
    float*    hB      = (float*)d_ws + off_hB;
    unsigned* recs1   = (unsigned*)d_ws + off_recs1;
    unsigned* recs2   = (unsigned*)d_ws + off_recs2;
    int2*     ovf2    = (int2*)((int*)d_ws + off_ovf2);
    unsigned* ovf1    = (unsigned*)d_ws + off_ovf1;
    int*      gcnt1   = (int*)d_ws + off_gcnt1;
    int*      gcnt2   = (int*)d_ws + off_gcnt2;
    int*      ovfcnts = (int*)d_ws + off_cnts;

    // zero gcnt1 + gcnt2 + ovf counters (contiguous)
    hipMemsetAsync(gcnt1, 0, ((size_t)NW + (size_t)4 * NBD + 2) * sizeof(int), stream);

    int gb_init = min((n * 16 + BLK - 1) / BLK, 2048);
    hipLaunchKernelGGL(k_init_h, dim3(gb_init), dim3(BLK), 0, stream, x, hA, n);

    int gbA = (total + 512 * IPTA - 1) / (512 * IPTA);   // 391
    hipLaunchKernelGGL(k_win, dim3(gbA), dim3(512), 0, stream,
                       orders, total, epo, NW, gcnt1, recs1, ovfcnts + 0, ovf1);

    hipLaunchKernelGGL(k_bin2, dim3(NW), dim3(512), 0, stream,
                       edge_i, ne, gcnt1, recs1, NW, NBD,
                       gcnt2, recs2, ovfcnts + 1, ovf2);

    float* cur = hA; float* nxt = hB;
    for (int s = 0; s < n_orders; ++s) {
        bool fin = (s == n_orders - 1);
        if (fin) {
            hipLaunchKernelGGL((k_agg2<true>), dim3(NBD), dim3(512), 0, stream,
                               cur, nxt, gcnt2 + (size_t)s * NBD,
                               recs2 + (size_t)s * NBD * CAPB, w_mp, b_mp,
                               w_out, b_out, out, n);
            hipLaunchKernelGGL(k_fix_final, dim3(8), dim3(256), 0, stream,
                               cur, out, edge_i, ne,
                               ovfcnts + 0, ovf1, ovfcnts + 1, ovf2,
                               w_mp, b_mp, w_out, s);
        } else {
            hipLaunchKernelGGL((k_agg2<false>), dim3(NBD), dim3(512), 0, stream,
                               cur, nxt, gcnt2 + (size_t)s * NBD,
                               recs2 + (size_t)s * NBD * CAPB, w_mp, b_mp,
                               w_out, b_out, out, n);
            hipLaunchKernelGGL(k_fix, dim3(8), dim3(256), 0, stream,
                               cur, nxt, edge_i, ne,
                               ovfcnts + 0, ovf1, ovfcnts + 1, ovf2,
                               w_mp, b_mp, s);
            float* t2 = cur; cur = nxt; nxt = t2;
        }
    }
}